// Round 10
// baseline (176.075 us; speedup 1.0000x reference)
//
#include <hip/hip_runtime.h>

#define N_NODES 50000
#define D 128
#define KDIM 256
#define SCAN_B 256
#define SCAN_NB ((N_NODES + SCAN_B - 1) / SCAN_B)  // 196
#define CW_NB 256                                   // convert_w blocks
#define CX_NB ((N_NODES * 32) / 256)                // 6250 convert_x blocks
#define NR 8                                        // XCD bins
#define RNG ((N_NODES + NR - 1) / NR)               // 6250 nodes per bin
#define SC_CHUNK 4096                               // edges per scatter chunk

typedef __attribute__((ext_vector_type(8))) short short8;
typedef __attribute__((ext_vector_type(4))) float f32x4;

__device__ __forceinline__ unsigned short f2bf(float f) {
    unsigned int u = __builtin_bit_cast(unsigned int, f);
    u += 0x7FFFu + ((u >> 16) & 1u);
    return (unsigned short)(u >> 16);
}
__device__ __forceinline__ float bflo(unsigned int u) {
    return __builtin_bit_cast(float, u << 16);
}
__device__ __forceinline__ float bfhi(unsigned int u) {
    return __builtin_bit_cast(float, u & 0xFFFF0000u);
}

// ---------------------------------------------------------------------------
// prep: fused {zero cnt+flags | convert W | convert x}, branch per block range
// ---------------------------------------------------------------------------
__global__ void prep_kernel(int* __restrict__ cnt, int* __restrict__ bflag,
                            const float* __restrict__ Wl1, const float* __restrict__ Wr1,
                            const float* __restrict__ Wl2, const float* __restrict__ Wr2,
                            unsigned short* __restrict__ Wt1, unsigned short* __restrict__ Wt2,
                            const float* __restrict__ x, unsigned short* __restrict__ A) {
    const int bid = blockIdx.x;
    const int t = threadIdx.x;
    if (bid < SCAN_NB) {
        int i = bid * SCAN_B + t;
        if (i < N_NODES) cnt[i] = 0;
        if (t == 0) bflag[bid] = 0;
    } else if (bid < SCAN_NB + CW_NB) {
        if (t < 128) {
            int wb = bid - SCAN_NB;
            int layer = wb >> 7;
            int j = wb & 127;
            const float* Wl = layer ? Wl2 : Wl1;
            const float* Wr = layer ? Wr2 : Wr1;
            unsigned short* Wt = layer ? Wt2 : Wt1;
            Wt[(size_t)j * KDIM + t]     = f2bf(Wl[t * D + j]);
            Wt[(size_t)j * KDIM + D + t] = f2bf(Wr[t * D + j]);
        }
    } else {
        int g = (bid - SCAN_NB - CW_NB) * 256 + t;
        int n = g >> 5;
        int c4 = (g & 31) * 4;
        if (n < N_NODES) {
            float4 v = *reinterpret_cast<const float4*>(&x[(size_t)n * D + c4]);
            ushort4 o;
            o.x = f2bf(v.x); o.y = f2bf(v.y); o.z = f2bf(v.z); o.w = f2bf(v.w);
            *reinterpret_cast<ushort4*>(&A[(size_t)n * KDIM + D + c4]) = o;
        }
    }
}

// ---------------------------------------------------------------------------
// CSR build step 1: histogram of dst
// ---------------------------------------------------------------------------
__global__ void hist_kernel(const int* __restrict__ dst,
                            int* __restrict__ cnt, int n_edges) {
    int e = blockIdx.x * blockDim.x + threadIdx.x;
    if (e < n_edges) atomicAdd(&cnt[dst[e]], 1);
}

// ---------------------------------------------------------------------------
// CSR build step 2: single-pass exclusive scan (decoupled lookback)
// ---------------------------------------------------------------------------
__global__ __launch_bounds__(SCAN_B)
void scan_lookback(const int* __restrict__ cnt,
                   int* __restrict__ rowptr,
                   int* __restrict__ cursor,
                   int* __restrict__ bagg,
                   int* __restrict__ bflag, int n_edges) {
    __shared__ int s[SCAN_B];
    __shared__ int sh_prefix;
    const int bid = blockIdx.x;
    const int t = threadIdx.x;
    const int i = bid * SCAN_B + t;
    const int v = (i < N_NODES) ? cnt[i] : 0;
    s[t] = v;
    __syncthreads();
    for (int off = 1; off < SCAN_B; off <<= 1) {
        int tmp = (t >= off) ? s[t - off] : 0;
        __syncthreads();
        s[t] += tmp;
        __syncthreads();
    }
    if (t == 0) {
        bagg[bid] = s[SCAN_B - 1];
        __hip_atomic_store(&bflag[bid], 1, __ATOMIC_RELEASE,
                           __HIP_MEMORY_SCOPE_AGENT);
        sh_prefix = 0;
        if (bid == 0) rowptr[N_NODES] = n_edges;  // every dst in [0,N)
    }
    if (bid > 0 && t < 64) {
        int part = 0;
        for (int j = t; j < bid; j += 64) {
            while (__hip_atomic_load(&bflag[j], __ATOMIC_ACQUIRE,
                                     __HIP_MEMORY_SCOPE_AGENT) == 0) {}
            part += bagg[j];
        }
#pragma unroll
        for (int off = 32; off > 0; off >>= 1) part += __shfl_down(part, off);
        if (t == 0) sh_prefix = part;
    }
    __syncthreads();
    if (i < N_NODES) {
        int ex = sh_prefix + s[t] - v;
        rowptr[i] = ex;
        cursor[i] = ex;
    }
}

// ---------------------------------------------------------------------------
// CSR build step 3: XCD-binned scatter (write locality per dst range)
// ---------------------------------------------------------------------------
__global__ void scatter_binned(const int* __restrict__ src,
                               const int* __restrict__ dst,
                               int* __restrict__ cursor,
                               int* __restrict__ col, int n_edges) {
    const int r = blockIdx.x & (NR - 1);
    const int c = blockIdx.x >> 3;
    const int lo = r * RNG;
    const int hi = min(N_NODES, lo + RNG);
    const int ebase = c * SC_CHUNK;
    const int eend = min(n_edges, ebase + SC_CHUNK);
    for (int e = ebase + threadIdx.x; e < eend; e += 256) {
        int d = dst[e];
        if (d >= lo && d < hi) {
            int p = atomicAdd(&cursor[d], 1);
            col[p] = src[e];
        }
    }
}

// ---------------------------------------------------------------------------
// Fused SAGE layer, 512 threads (8 waves):
//  stage 1: 32 quarter-waves; each does 2 of the block's 64 node rows;
//           4 independent 256B row-gathers in flight per iteration;
//           means stored to XOR-swizzled LDS.
//  stage 2: MFMA GEMM; 8 waves x 16 output cols; mean term from LDS,
//           self term from global.
// LAYER 1: feats at A[.][D..2D), h (bf16) -> A[.][0..D)  (disjoint cols).
// LAYER 2: feats at A[.][0..D), out fp32.
// ---------------------------------------------------------------------------
template <int LAYER>
__global__ __launch_bounds__(512)
void sage_layer_fused(const unsigned short* __restrict__ A,
                      unsigned short* __restrict__ A_wr,
                      const int* __restrict__ rowptr,
                      const int* __restrict__ col,
                      const unsigned short* __restrict__ Wt,
                      const float* __restrict__ bias,
                      float* __restrict__ out_f32) {
    constexpr int FEAT = (LAYER == 1) ? D : 0;
    __shared__ unsigned short ms[64 * D];  // 16 KB, swizzled [64][128] bf16

    const int row0 = blockIdx.x * 64;
    const int tid = threadIdx.x;

    // ---- stage 1: mean-aggregate; quarter-wave (16 lanes) per node ----
    {
        const int qid = tid >> 4;    // 0..31
        const int lq = tid & 15;     // owns 16B = 8 cols of the 256B row
        for (int s = 0; s < 2; ++s) {
            const int lr = s * 32 + qid;    // local row 0..63
            const int node = row0 + lr;
            float a[8] = {0.f, 0.f, 0.f, 0.f, 0.f, 0.f, 0.f, 0.f};
            int deg = 0;
            if (node < N_NODES) {
                const int e0 = rowptr[node];
                deg = rowptr[node + 1] - e0;
                for (int base = 0; base < deg; base += 16) {
                    const int nch = min(16, deg - base);
                    int myc = (lq < nch) ? col[e0 + base + lq] : 0;
                    int i = 0;
                    for (; i + 3 < nch; i += 4) {  // 4 gathers in flight
                        const int s0 = __shfl(myc, i, 16);
                        const int s1 = __shfl(myc, i + 1, 16);
                        const int s2 = __shfl(myc, i + 2, 16);
                        const int s3 = __shfl(myc, i + 3, 16);
                        const uint4 v0 = *reinterpret_cast<const uint4*>(
                            &A[(size_t)s0 * KDIM + FEAT + lq * 8]);
                        const uint4 v1 = *reinterpret_cast<const uint4*>(
                            &A[(size_t)s1 * KDIM + FEAT + lq * 8]);
                        const uint4 v2 = *reinterpret_cast<const uint4*>(
                            &A[(size_t)s2 * KDIM + FEAT + lq * 8]);
                        const uint4 v3 = *reinterpret_cast<const uint4*>(
                            &A[(size_t)s3 * KDIM + FEAT + lq * 8]);
                        a[0] += (bflo(v0.x) + bflo(v1.x)) + (bflo(v2.x) + bflo(v3.x));
                        a[1] += (bfhi(v0.x) + bfhi(v1.x)) + (bfhi(v2.x) + bfhi(v3.x));
                        a[2] += (bflo(v0.y) + bflo(v1.y)) + (bflo(v2.y) + bflo(v3.y));
                        a[3] += (bfhi(v0.y) + bfhi(v1.y)) + (bfhi(v2.y) + bfhi(v3.y));
                        a[4] += (bflo(v0.z) + bflo(v1.z)) + (bflo(v2.z) + bflo(v3.z));
                        a[5] += (bfhi(v0.z) + bfhi(v1.z)) + (bfhi(v2.z) + bfhi(v3.z));
                        a[6] += (bflo(v0.w) + bflo(v1.w)) + (bflo(v2.w) + bflo(v3.w));
                        a[7] += (bfhi(v0.w) + bfhi(v1.w)) + (bfhi(v2.w) + bfhi(v3.w));
                    }
                    for (; i < nch; ++i) {
                        const int s0 = __shfl(myc, i, 16);
                        const uint4 v0 = *reinterpret_cast<const uint4*>(
                            &A[(size_t)s0 * KDIM + FEAT + lq * 8]);
                        a[0] += bflo(v0.x); a[1] += bfhi(v0.x);
                        a[2] += bflo(v0.y); a[3] += bfhi(v0.y);
                        a[4] += bflo(v0.z); a[5] += bfhi(v0.z);
                        a[6] += bflo(v0.w); a[7] += bfhi(v0.w);
                    }
                }
            }
            const float inv = deg > 0 ? 1.0f / (float)deg : 0.0f;
            uint4 o;
            o.x = ((unsigned int)f2bf(a[1] * inv) << 16) | f2bf(a[0] * inv);
            o.y = ((unsigned int)f2bf(a[3] * inv) << 16) | f2bf(a[2] * inv);
            o.z = ((unsigned int)f2bf(a[5] * inv) << 16) | f2bf(a[4] * inv);
            o.w = ((unsigned int)f2bf(a[7] * inv) << 16) | f2bf(a[6] * inv);
            // XOR-swizzled store: byte = lr*256 + ((lq*16) ^ ((lr&7)<<4))
            char* rowb = reinterpret_cast<char*>(ms) + lr * 256;
            *reinterpret_cast<uint4*>(rowb + ((lq * 16) ^ ((lr & 7) << 4))) = o;
        }
    }
    __syncthreads();

    // ---- stage 2: MFMA GEMM; wave w owns 16 output cols, 64 rows/block ----
    const int w = tid >> 6;            // 0..7
    const int lane = tid & 63;
    const int l16 = lane & 15;
    const int lk = lane >> 4;          // 0..3
    const int wc = w * 16;             // wave col base

    short8 bfrag[8];
#pragma unroll
    for (int kk = 0; kk < 8; ++kk)
        bfrag[kk] = *reinterpret_cast<const short8*>(
            &Wt[(size_t)(wc + l16) * KDIM + kk * 32 + lk * 8]);

    f32x4 acc[4];
#pragma unroll
    for (int r = 0; r < 4; ++r) acc[r] = (f32x4)0.0f;

    // kk 0..3: mean term (k=0..127) from swizzled LDS
#pragma unroll
    for (int kk = 0; kk < 4; ++kk) {
        short8 af[4];
#pragma unroll
        for (int r = 0; r < 4; ++r) {
            const int lr = r * 16 + l16;
            const int cb = kk * 64 + lk * 16;  // byte col within row
            const char* rowb = reinterpret_cast<const char*>(ms) + lr * 256;
            af[r] = *reinterpret_cast<const short8*>(
                rowb + (cb ^ ((lr & 7) << 4)));
        }
#pragma unroll
        for (int r = 0; r < 4; ++r)
            acc[r] = __builtin_amdgcn_mfma_f32_16x16x32_bf16(
                af[r], bfrag[kk], acc[r], 0, 0, 0);
    }

    // kk 4..7: self term (k=128..255) from global features
#pragma unroll
    for (int kk = 4; kk < 8; ++kk) {
        short8 af[4];
#pragma unroll
        for (int r = 0; r < 4; ++r) {
            int row = row0 + r * 16 + l16;
            if (row >= N_NODES) row = N_NODES - 1;  // clamp; values unused
            af[r] = *reinterpret_cast<const short8*>(
                &A[(size_t)row * KDIM + FEAT + (kk - 4) * 32 + lk * 8]);
        }
#pragma unroll
        for (int r = 0; r < 4; ++r)
            acc[r] = __builtin_amdgcn_mfma_f32_16x16x32_bf16(
                af[r], bfrag[kk], acc[r], 0, 0, 0);
    }

    // epilogue: C/D layout col=lane&15, row=(lane>>4)*4+reg  [verified m89/m91]
    {
        const int colj = wc + l16;
        const float bv = bias[colj];
#pragma unroll
        for (int r = 0; r < 4; ++r) {
#pragma unroll
            for (int q = 0; q < 4; ++q) {
                int row = row0 + r * 16 + lk * 4 + q;
                if (row < N_NODES) {
                    float v = acc[r][q] + bv;
                    v = v > 0.f ? v : 0.f;
                    if (LAYER == 1)
                        A_wr[(size_t)row * KDIM + colj] = f2bf(v);  // h -> cols 0..127
                    else
                        out_f32[(size_t)row * D + colj] = v;
                }
            }
        }
    }
}

extern "C" void kernel_launch(void* const* d_in, const int* in_sizes, int n_in,
                              void* d_out, int out_size, void* d_ws, size_t ws_size,
                              hipStream_t stream) {
    const float* x   = (const float*)d_in[0];
    const int*   ei  = (const int*)  d_in[1];
    const float* W1l = (const float*)d_in[2];
    const float* b1  = (const float*)d_in[3];
    const float* W1r = (const float*)d_in[4];
    const float* W2l = (const float*)d_in[5];
    const float* b2  = (const float*)d_in[6];
    const float* W2r = (const float*)d_in[7];
    float*       out = (float*)d_out;

    const int n_edges = in_sizes[1] / 2;
    const int* src = ei;
    const int* dst = ei + n_edges;

    // workspace layout (A first for 16B alignment)
    char* ws = (char*)d_ws;
    unsigned short* A   = (unsigned short*)ws;                 // N*256 bf16
    unsigned short* Wt1 = A + (size_t)N_NODES * KDIM;          // 128*256
    unsigned short* Wt2 = Wt1 + 128 * KDIM;                    // 128*256
    int* cnt    = (int*)(Wt2 + 128 * KDIM);                    // N
    int* rowptr = cnt + N_NODES;                               // N+1
    int* cursor = rowptr + (N_NODES + 1);                      // N
    int* bagg   = cursor + N_NODES;                            // SCAN_NB
    int* bflag  = bagg + SCAN_NB;                              // SCAN_NB
    int* col    = bflag + SCAN_NB;                             // E

    // ---- prep: zero cnt/flags + convert W + convert x (1 launch) ----
    prep_kernel<<<SCAN_NB + CW_NB + CX_NB, 256, 0, stream>>>(
        cnt, bflag, W1l, W1r, W2l, W2r, Wt1, Wt2, x, A);

    // ---- CSR build: hist -> single-pass scan -> binned scatter ----
    hist_kernel<<<(n_edges + 255) / 256, 256, 0, stream>>>(dst, cnt, n_edges);
    scan_lookback<<<SCAN_NB, SCAN_B, 0, stream>>>(cnt, rowptr, cursor, bagg,
                                                  bflag, n_edges);
    const int nchunks = (n_edges + SC_CHUNK - 1) / SC_CHUNK;
    scatter_binned<<<nchunks * NR, 256, 0, stream>>>(src, dst, cursor, col,
                                                     n_edges);

    const int grid = (N_NODES + 63) / 64;  // 782

    // ---- fused layers ----
    sage_layer_fused<1><<<grid, 512, 0, stream>>>(A, A, rowptr, col, Wt1, b1,
                                                  nullptr);
    sage_layer_fused<2><<<grid, 512, 0, stream>>>(A, A, rowptr, col, Wt2, b2,
                                                  out);
}